// Round 3
// baseline (488.802 us; speedup 1.0000x reference)
//
#include <hip/hip_runtime.h>

// Problem constants (mirrors reference)
#define NI    32              // batch
#define HH    1024
#define WW    1024
#define BHW   16              // pool window
#define BS    14              // block stride
#define NBH   73              // block count h
#define NBW   73              // block count w
#define NCHUNK (NI * NBH)     // 2336 block-rows
#define TOTAL  (NI * NBH * NBW) // 170528
#define ROWDW  (3 * NBW)      // 219 output dwords per chunk

struct umask2 { unsigned long long x, y; };

__device__ __forceinline__ float4 max4(float4 a, float4 b) {
    return make_float4(fmaxf(a.x, b.x), fmaxf(a.y, b.y),
                       fmaxf(a.z, b.z), fmaxf(a.w, b.w));
}

// Speculative "all 73 windows active" enumeration write for one chunk:
// out rows [chunk*73, chunk*73+73) = (n, by, 0..72). 219 consecutive dword
// stores by threads 0..218 — coalesced. This IS the final answer whenever
// the grand total equals TOTAL (P(otherwise) ~ 3e-7 on uniform data).
__device__ __forceinline__ void write_full_row(int* __restrict__ out,
                                               int chunk, int n, int by, int tid) {
    if (tid < ROWDW) {
        const int q = tid / 3;            // bx
        const int comp = tid - 3 * q;     // 0:n 1:by 2:bx
        int v;
        if (comp == 0) v = n; else if (comp == 1) v = by; else v = q;
        out[(size_t)chunk * ROWDW + tid] = v;
    }
}

// ---------------------------------------------------------------------------
// Single fused kernel: one workgroup per (n, by) block-row.
//
// Phase 1 (common, ~96.4%): load 6 window rows as independent float4 loads
// (single HBM round-trip), then ONE conservative all-windows-hit test:
// per-lane "colmax4 > 0.9" ballots give a 256-bit map (1 bit = 4 cols);
// window bx (cols [14bx-1, 14bx+14]) tests only the 3-4 ballot bits FULLY
// inside the window (>=12 interior cols) — a set bit proves window-max > 0.9
// with no false positives. P(miss | 6 rows, uniform) ~ 73 * 0.9^72 ~ 3.6%.
// If all 73 prove: write all-ones mask, count=73, and the speculative
// enumeration triples. One load round + 2 barrier ops.
//
// Phase 2 (rare, ~3.6%): load remaining rows, exact colmax + horizontal max.
// Full chunks still write their enumeration (identical to speculative form).
//
// Completion: every block does __threadfence() + ticket atomicAdd. The LAST
// block sums counts[]; if the grand total != TOTAL (P ~ 3e-7), it alone
// re-derives the entire output with the verified stable-scatter + -1 tail
// algorithm, overwriting all speculative rows. Otherwise output is already
// exact and complete — no second kernel launch needed.
__global__ __launch_bounds__(256, 8) void pool_kernel(const float* __restrict__ mask,
                                                      umask2* __restrict__ masks,
                                                      int* __restrict__ counts,
                                                      int* __restrict__ done_ctr,
                                                      int* __restrict__ out) {
    const int chunk = blockIdx.x;         // n*NBH + by
    const int n  = chunk / NBH;
    const int by = chunk % NBH;
    const int tid  = threadIdx.x;
    const int lane = tid & 63;
    const int wave = tid >> 6;

    __shared__ float colmax[WW];
    __shared__ unsigned long long wb[4];
    __shared__ unsigned long long sm0, sm1;
    __shared__ int slast;
    __shared__ int s_e;

    const int r0 = by * BS - 1;           // padded window start (pad=1)
    const int rs = max(r0, 0);            // only by==0 clips; bottom never does
    const int nr = (by > 0) ? 16 : 15;    // valid rows in window
    const float* p = mask + (size_t)n * HH * WW + (size_t)rs * WW + tid * 4;

    // ---- phase 1: 6 independent row loads, full ILP ----
    const float4 a0 = *(const float4*)(p + 0 * (size_t)WW);
    const float4 a1 = *(const float4*)(p + 1 * (size_t)WW);
    const float4 a2 = *(const float4*)(p + 2 * (size_t)WW);
    const float4 a3 = *(const float4*)(p + 3 * (size_t)WW);
    const float4 a4 = *(const float4*)(p + 4 * (size_t)WW);
    const float4 a5 = *(const float4*)(p + 5 * (size_t)WW);
    float4 m = max4(max4(max4(a0, a1), max4(a2, a3)), max4(a4, a5));

    const float mm = fmaxf(fmaxf(m.x, m.y), fmaxf(m.z, m.w));
    const unsigned long long bal = __ballot(mm > 0.9f);
    if (lane == 0) wb[wave] = bal;
    __syncthreads();

    bool whit = true;                     // tid >= 73 -> vacuously true
    if (tid < NBW) {
        const int c0 = tid * BS;
        const int lo = (c0 + 2) >> 2;     // first bit fully inside window
        const int hi = (c0 + 11) >> 2;    // last bit fully inside window
        const int w0 = lo >> 6, sh = lo & 63;
        unsigned long long bits = wb[w0] >> sh;
        if (w0 < 3 && sh) bits |= wb[w0 + 1] << (64 - sh);
        const int nb = hi - lo + 1;       // 3 or 4
        whit = (bits & ((1ull << nb) - 1ull)) != 0ull;
    }
    const bool done = __syncthreads_and((int)whit) != 0;

    if (done) {                           // exact: every window proved > 0.9
        if (tid == 0) {
            umask2 mk; mk.x = ~0ull; mk.y = (1ull << (NBW - 64)) - 1ull;
            masks[chunk] = mk;
            counts[chunk] = NBW;
        }
        write_full_row(out, chunk, n, by, tid);
    } else {
        // ---- phase 2 (rare): accumulate remaining rows, exact fallback ----
        for (int r = 6; r < nr; ++r)
            m = max4(m, *(const float4*)(p + (size_t)r * WW));

        const int c = tid * 4;
        colmax[c + 0] = m.x;
        colmax[c + 1] = m.y;
        colmax[c + 2] = m.z;
        colmax[c + 3] = m.w;
        __syncthreads();

        int f = 0;
        if (tid < NBW) {
            const int c0 = tid * BS - 1;
            float mx = colmax[max(c0, 0)];    // dc=0 clamped; dc>=1 always >= 0
            #pragma unroll
            for (int dc = 1; dc < BHW; ++dc) mx = fmaxf(mx, colmax[c0 + dc]);
            f = (mx > 0.9f) ? 1 : 0;
        }
        const unsigned long long b = __ballot(f);
        if (wave == 0 && lane == 0) sm0 = b;  // bits for bx 0..63
        if (wave == 1 && lane == 0) sm1 = b;  // bits for bx 64..72
        __syncthreads();

        const int cnt = __popcll(sm0) + __popcll(sm1);
        if (tid == 0) {
            umask2 mk; mk.x = sm0; mk.y = sm1;
            masks[chunk] = mk;
            counts[chunk] = cnt;
        }
        if (cnt == NBW)                        // conservative test missed, but
            write_full_row(out, chunk, n, by, tid); // full: speculation valid
    }

    // ---- completion protocol: last block verifies grand total ----
    __threadfence();                      // release masks/counts/out writes
    if (tid == 0) {
        const int ticket = atomicAdd(done_ctr, 1);
        slast = (ticket == NCHUNK - 1) ? 1 : 0;
    }
    __syncthreads();
    if (!slast) return;                   // block-uniform

    // LAST block: acquire all other blocks' writes, verify grand total.
    __threadfence();
    int partial = 0;
    for (int i = tid; i < NCHUNK; i += 256) partial += counts[i];
    #pragma unroll
    for (int off = 32; off > 0; off >>= 1) partial += __shfl_down(partial, off, 64);
    __shared__ int wsum[4];
    if (lane == 0) wsum[wave] = partial;
    __syncthreads();
    const int grand = wsum[0] + wsum[1] + wsum[2] + wsum[3];
    if (grand == TOTAL) return;           // speculative output already exact

    // ---- P ~ 3e-7 path: serialized verified stable scatter + -1 tail ----
    if (tid == 0) s_e = 0;
    __syncthreads();
    for (int ch = 0; ch < NCHUNK; ++ch) {
        const umask2 mk = masks[ch];      // broadcast, L2-hot
        const int cn  = ch / NBH;
        const int cby = ch % NBH;
        const int e = s_e;
        if (tid < NBW) {
            int f, prefix;
            if (tid < 64) {
                f = (int)((mk.x >> tid) & 1ull);
                prefix = __popcll(mk.x & ((1ull << tid) - 1ull));
            } else {
                const int t = tid - 64;
                f = (int)((mk.y >> t) & 1ull);
                prefix = __popcll(mk.x) + __popcll(mk.y & ((1ull << t) - 1ull));
            }
            if (f) {
                const int pos = e + prefix;
                out[3 * pos + 0] = cn;
                out[3 * pos + 1] = cby;
                out[3 * pos + 2] = tid;
            }
        }
        __syncthreads();
        if (tid == 0) s_e = e + __popcll(mk.x) + __popcll(mk.y);
        __syncthreads();
    }
    const int gt = s_e;                   // grand total (== grand)
    for (int i = 3 * gt + tid; i < 3 * TOTAL; i += 256) out[i] = -1;
}

// ---------------------------------------------------------------------------
extern "C" void kernel_launch(void* const* d_in, const int* in_sizes, int n_in,
                              void* d_out, int out_size, void* d_ws, size_t ws_size,
                              hipStream_t stream) {
    const float* mask = (const float*)d_in[0];
    int* out = (int*)d_out;

    // workspace layout: [masks: 2336 x 16B][counts: 2336 x 4B][done_ctr: 4B]
    umask2* masks = (umask2*)d_ws;
    int* counts = (int*)(masks + NCHUNK);
    int* done_ctr = counts + NCHUNK;

    (void)hipMemsetAsync(done_ctr, 0, sizeof(int), stream);  // graph node
    pool_kernel<<<NCHUNK, 256, 0, stream>>>(mask, masks, counts, done_ctr, out);
}

// Round 4
// 180.555 us; speedup vs baseline: 2.7072x; 2.7072x over previous
//
#include <hip/hip_runtime.h>

// Problem constants (mirrors reference)
#define NI    32              // batch
#define HH    1024
#define WW    1024
#define BHW   16              // pool window
#define BS    14              // block stride
#define NBH   73              // block count h
#define NBW   73              // block count w
#define NCHUNK (NI * NBH)     // 2336 block-rows
#define TOTAL  (NI * NBH * NBW) // 170528
#define ROWDW  (3 * NBW)      // 219 output dwords per chunk

struct umask2 { unsigned long long x, y; };

__device__ __forceinline__ float4 max4(float4 a, float4 b) {
    return make_float4(fmaxf(a.x, b.x), fmaxf(a.y, b.y),
                       fmaxf(a.z, b.z), fmaxf(a.w, b.w));
}

// Speculative "all 73 windows active" enumeration write for one chunk:
// out rows [chunk*73, chunk*73+73) = (n, by, 0..72). 219 consecutive dword
// stores by threads 0..218 — coalesced. This IS the final answer whenever
// the grand total equals TOTAL (P(otherwise) ~ 3e-7 on uniform data).
__device__ __forceinline__ void write_full_row(int* __restrict__ out,
                                               int chunk, int n, int by, int tid) {
    if (tid < ROWDW) {
        const int q = tid / 3;            // bx
        const int comp = tid - 3 * q;     // 0:n 1:by 2:bx
        int v;
        if (comp == 0) v = n; else if (comp == 1) v = by; else v = q;
        out[(size_t)chunk * ROWDW + tid] = v;
    }
}

// ---------------------------------------------------------------------------
// Kernel 1: one workgroup per (n, by) block-row. NO device-scope fences or
// atomics anywhere (round-3 post-mortem: __threadfence() in every block =
// per-block L2 writeback on non-coherent XCDs = +344 us. Kernel-boundary
// coherence is free; use it instead).
//
// Phase 1 (common, ~96.4%): load 6 window rows as independent float4 loads
// (single HBM round-trip), then ONE conservative all-windows-hit test:
// per-lane "colmax4 > 0.9" ballots give a 256-bit map (1 bit = 4 cols);
// window bx (cols [14bx-1, 14bx+14]) tests only the 3-4 ballot bits FULLY
// inside the window (>=12 interior cols) — a set bit proves window-max > 0.9
// with no false positives. P(miss | 6 rows, uniform) ~ 73 * 0.9^72 ~ 3.6%.
// If all 73 prove: write all-ones mask, count=73, speculative enumeration.
//
// Phase 2 (rare, ~3.6%): load remaining rows, exact colmax + horizontal max.
// Full chunks still write their enumeration (identical to speculative form).
__global__ __launch_bounds__(256, 8) void pool_kernel(const float* __restrict__ mask,
                                                      umask2* __restrict__ masks,
                                                      int* __restrict__ counts,
                                                      int* __restrict__ out) {
    const int chunk = blockIdx.x;         // n*NBH + by
    const int n  = chunk / NBH;
    const int by = chunk % NBH;
    const int tid  = threadIdx.x;
    const int lane = tid & 63;
    const int wave = tid >> 6;

    __shared__ float colmax[WW];
    __shared__ unsigned long long wb[4];
    __shared__ unsigned long long sm0, sm1;

    const int r0 = by * BS - 1;           // padded window start (pad=1)
    const int rs = max(r0, 0);            // only by==0 clips; bottom never does
    const int nr = (by > 0) ? 16 : 15;    // valid rows in window
    const float* p = mask + (size_t)n * HH * WW + (size_t)rs * WW + tid * 4;

    // ---- phase 1: 6 independent row loads, full ILP ----
    const float4 a0 = *(const float4*)(p + 0 * (size_t)WW);
    const float4 a1 = *(const float4*)(p + 1 * (size_t)WW);
    const float4 a2 = *(const float4*)(p + 2 * (size_t)WW);
    const float4 a3 = *(const float4*)(p + 3 * (size_t)WW);
    const float4 a4 = *(const float4*)(p + 4 * (size_t)WW);
    const float4 a5 = *(const float4*)(p + 5 * (size_t)WW);
    float4 m = max4(max4(max4(a0, a1), max4(a2, a3)), max4(a4, a5));

    const float mm = fmaxf(fmaxf(m.x, m.y), fmaxf(m.z, m.w));
    const unsigned long long bal = __ballot(mm > 0.9f);
    if (lane == 0) wb[wave] = bal;
    __syncthreads();

    bool whit = true;                     // tid >= 73 -> vacuously true
    if (tid < NBW) {
        const int c0 = tid * BS;
        const int lo = (c0 + 2) >> 2;     // first bit fully inside window
        const int hi = (c0 + 11) >> 2;    // last bit fully inside window
        const int w0 = lo >> 6, sh = lo & 63;
        unsigned long long bits = wb[w0] >> sh;
        if (w0 < 3 && sh) bits |= wb[w0 + 1] << (64 - sh);
        const int nb = hi - lo + 1;       // 3 or 4
        whit = (bits & ((1ull << nb) - 1ull)) != 0ull;
    }
    const bool done = __syncthreads_and((int)whit) != 0;

    if (done) {                           // exact: every window proved > 0.9
        if (tid == 0) {
            umask2 mk; mk.x = ~0ull; mk.y = (1ull << (NBW - 64)) - 1ull;
            masks[chunk] = mk;
            counts[chunk] = NBW;
        }
        write_full_row(out, chunk, n, by, tid);
        return;                           // block-uniform
    }

    // ---- phase 2 (rare): accumulate remaining rows, exact fallback ----
    for (int r = 6; r < nr; ++r)
        m = max4(m, *(const float4*)(p + (size_t)r * WW));

    const int c = tid * 4;
    colmax[c + 0] = m.x;
    colmax[c + 1] = m.y;
    colmax[c + 2] = m.z;
    colmax[c + 3] = m.w;
    __syncthreads();

    int f = 0;
    if (tid < NBW) {
        const int c0 = tid * BS - 1;
        float mx = colmax[max(c0, 0)];    // dc=0 clamped; dc>=1 always >= 0
        #pragma unroll
        for (int dc = 1; dc < BHW; ++dc) mx = fmaxf(mx, colmax[c0 + dc]);
        f = (mx > 0.9f) ? 1 : 0;
    }
    const unsigned long long b = __ballot(f);
    if (wave == 0 && lane == 0) sm0 = b;  // bits for bx 0..63
    if (wave == 1 && lane == 0) sm1 = b;  // bits for bx 64..72
    __syncthreads();

    const int cnt = __popcll(sm0) + __popcll(sm1);
    if (tid == 0) {
        umask2 mk; mk.x = sm0; mk.y = sm1;
        masks[chunk] = mk;
        counts[chunk] = cnt;
    }
    if (cnt == NBW)                        // conservative test missed, but
        write_full_row(out, chunk, n, by, tid); // full: speculation valid
}

// ---------------------------------------------------------------------------
// Kernel 2: SINGLE block. Kernel launch boundary (same stream) makes all of
// pool_kernel's writes visible — no fences needed. Sums counts (2336 ints,
// L2-hot); if grand total == TOTAL the speculative enumerations already in
// `out` ARE the exact answer -> return. Otherwise (P ~ 3e-7) this one block
// re-derives the entire output with the verified stable-scatter + -1 tail,
// overwriting every row.
__global__ __launch_bounds__(256) void verify_kernel(const umask2* __restrict__ masks,
                                                     const int* __restrict__ counts,
                                                     int* __restrict__ out) {
    const int tid  = threadIdx.x;
    const int lane = tid & 63;
    const int wave = tid >> 6;

    __shared__ int wsum[4];
    __shared__ int s_e;

    int partial = 0;
    for (int i = tid; i < NCHUNK; i += 256) partial += counts[i];
    #pragma unroll
    for (int off = 32; off > 0; off >>= 1) partial += __shfl_down(partial, off, 64);
    if (lane == 0) wsum[wave] = partial;
    __syncthreads();
    const int grand = wsum[0] + wsum[1] + wsum[2] + wsum[3];
    if (grand == TOTAL) return;           // speculative output already exact

    // ---- P ~ 3e-7 path: serialized verified stable scatter + -1 tail ----
    if (tid == 0) s_e = 0;
    __syncthreads();
    for (int ch = 0; ch < NCHUNK; ++ch) {
        const umask2 mk = masks[ch];      // broadcast, L2-hot
        const int cn  = ch / NBH;
        const int cby = ch % NBH;
        const int e = s_e;
        if (tid < NBW) {
            int f, prefix;
            if (tid < 64) {
                f = (int)((mk.x >> tid) & 1ull);
                prefix = __popcll(mk.x & ((1ull << tid) - 1ull));
            } else {
                const int t = tid - 64;
                f = (int)((mk.y >> t) & 1ull);
                prefix = __popcll(mk.x) + __popcll(mk.y & ((1ull << t) - 1ull));
            }
            if (f) {
                const int pos = e + prefix;
                out[3 * pos + 0] = cn;
                out[3 * pos + 1] = cby;
                out[3 * pos + 2] = tid;
            }
        }
        __syncthreads();
        if (tid == 0) s_e = e + __popcll(mk.x) + __popcll(mk.y);
        __syncthreads();
    }
    const int gt = s_e;                   // grand total (== grand)
    for (int i = 3 * gt + tid; i < 3 * TOTAL; i += 256) out[i] = -1;
}

// ---------------------------------------------------------------------------
extern "C" void kernel_launch(void* const* d_in, const int* in_sizes, int n_in,
                              void* d_out, int out_size, void* d_ws, size_t ws_size,
                              hipStream_t stream) {
    const float* mask = (const float*)d_in[0];
    int* out = (int*)d_out;

    // workspace layout: [masks: 2336 x 16B][counts: 2336 x 4B]
    umask2* masks = (umask2*)d_ws;
    int* counts = (int*)(masks + NCHUNK);

    pool_kernel<<<NCHUNK, 256, 0, stream>>>(mask, masks, counts, out);
    verify_kernel<<<1, 256, 0, stream>>>(masks, counts, out);
}